// Round 2
// baseline (307.059 us; speedup 1.0000x reference)
//
#include <hip/hip_runtime.h>

// l=8, p=1, m=4096, n=1024. One thread owns one row (nonlinear recurrence
// -> no intra-row parallelism while bit-exact). 32768 rows = 512 waves.
// Block = 1 wave (64 rows). Explicit LDS ring (8 x 4KB) filled by
// global_load_lds with hand-counted s_waitcnt vmcnt(N) -- the compiler
// refuses to hold a deep VGPR pipeline (round 1: VGPR 88 < needed 128,
// perf flat), so scheduling is taken out of its hands.
//
// Staging instr q of chunk c: lane L loads 16B of row 16q + L/4,
// col-group (L&3) ^ (((L>>2)>>1)&3), into linear LDS slot 64q + L.
// => per instr: 16 rows x 64B contiguous = 16 cache lines (4x better
//    coalescing than the old 64-line diverged loads).
// => read-back slot for (row r, colgrp g): 64*(r>>4) + 4*(r&15) + (g ^ ((r>>1)&3))
//    bank-group = slot%8 spans all 8 residues per 16-lane phase -> ds_read_b128
//    is conflict-free (2-way inherent only).
//
// vmcnt bookkeeping (4 gload_lds + 4 stores = 8 vmem events per iter,
// STAGE placed right after the lgkm wait, stores at iter end):
//   prologue stages chunks 0..6 (28 instrs)
//   head  c=0..6 : W = 24+4c  (24,28,32,36,40,44,48)
//   steady c=7..56: W = 52    (load(c) has exactly 52 instrs after it)
//   tail  c=57..63: W = 280-4c (52,48,44,40,36,32,28)
// Max outstanding 60 <= 63 (vmcnt field limit).

#define N_COLS 1024
#define NCHUNK 64
#define NBUF 8

#define WAITVM(n) asm volatile("s_waitcnt vmcnt(" #n ")" ::: "memory")
#define WAITLGKM0() asm volatile("s_waitcnt lgkmcnt(0)" ::: "memory")

__device__ __forceinline__ float stepf(float w, float x, float a, float b) {
    // Match numpy fp32 exactly: (w + (a/w)) - (b*x), RN, IEEE divide, no fma.
    return __fsub_rn(__fadd_rn(w, __fdiv_rn(a, w)), __fmul_rn(b, x));
}

__global__ __launch_bounds__(64) void DDK_77644418777662_kernel(
    const float* __restrict__ in, float* __restrict__ out,
    const float* __restrict__ alpha, const float* __restrict__ beta,
    int n_rows) {
    __shared__ float lds[NBUF * 1024];  // 8 x 4KB chunk buffers

    const int lane = threadIdx.x;
    const int row_base = blockIdx.x * 64;
    if (row_base >= n_rows) return;  // block-uniform (n_rows % 64 == 0)

    const float a = alpha[0];
    const float b = beta[0];
    // Drain the alpha/beta loads so the vmcnt arithmetic below is exact.
    asm volatile("s_waitcnt vmcnt(0) lgkmcnt(0)" ::: "memory");

    // --- staging source pointers (per-lane, swizzled col-group) ---
    const int t = lane >> 2;
    const int u = lane & 3;
    const int c4 = u ^ ((t >> 1) & 3);
    const float* pb0 = in + (size_t)(row_base + t) * N_COLS + c4 * 4;
    const float* pb1 = pb0 + 16 * N_COLS;
    const float* pb2 = pb0 + 32 * N_COLS;
    const float* pb3 = pb0 + 48 * N_COLS;

    // --- read-back slots (float index within a chunk buffer) ---
    const int s2 = (lane >> 1) & 3;
    const int sbase = 64 * (lane >> 4) + 4 * (lane & 15);
    const int sl0 = (sbase + (0 ^ s2)) * 4;
    const int sl1 = (sbase + (1 ^ s2)) * 4;
    const int sl2 = (sbase + (2 ^ s2)) * 4;
    const int sl3 = (sbase + (3 ^ s2)) * 4;

    float* outp = out + (size_t)(row_base + lane) * N_COLS;

#define STAGE(c) do {                                                          \
    float* dst_ = &lds[((c) & 7) * 1024];                                      \
    __builtin_amdgcn_global_load_lds(                                          \
        (const __attribute__((address_space(1))) void*)(pb0 + (c) * 16),       \
        (__attribute__((address_space(3))) void*)(dst_ + 0), 16, 0, 0);        \
    __builtin_amdgcn_global_load_lds(                                          \
        (const __attribute__((address_space(1))) void*)(pb1 + (c) * 16),       \
        (__attribute__((address_space(3))) void*)(dst_ + 256), 16, 0, 0);      \
    __builtin_amdgcn_global_load_lds(                                          \
        (const __attribute__((address_space(1))) void*)(pb2 + (c) * 16),       \
        (__attribute__((address_space(3))) void*)(dst_ + 512), 16, 0, 0);      \
    __builtin_amdgcn_global_load_lds(                                          \
        (const __attribute__((address_space(1))) void*)(pb3 + (c) * 16),       \
        (__attribute__((address_space(3))) void*)(dst_ + 768), 16, 0, 0);      \
} while (0)

    float w = 1.0f;

#define BODY(c, DO_LOAD) do {                                                  \
    const float* bufp_ = &lds[((c) & 7) * 1024];                               \
    float4 xa_ = *(const float4*)(bufp_ + sl0);                                \
    float4 xb_ = *(const float4*)(bufp_ + sl1);                                \
    float4 xc_ = *(const float4*)(bufp_ + sl2);                                \
    float4 xd_ = *(const float4*)(bufp_ + sl3);                                \
    WAITLGKM0();                                                               \
    if (DO_LOAD) STAGE((c) + 7);                                               \
    float x_[16] = {xa_.x, xa_.y, xa_.z, xa_.w, xb_.x, xb_.y, xb_.z, xb_.w,    \
                    xc_.x, xc_.y, xc_.z, xc_.w, xd_.x, xd_.y, xd_.z, xd_.w};   \
    float o_[16];                                                              \
    o_[0] = w;                                                                 \
    _Pragma("unroll")                                                          \
    for (int i_ = 1; i_ < 16; ++i_) { w = stepf(w, x_[i_ - 1], a, b); o_[i_] = w; } \
    w = stepf(w, x_[15], a, b);                                                \
    float4* op_ = (float4*)(outp + (c) * 16);                                  \
    op_[0] = make_float4(o_[0], o_[1], o_[2], o_[3]);                          \
    op_[1] = make_float4(o_[4], o_[5], o_[6], o_[7]);                          \
    op_[2] = make_float4(o_[8], o_[9], o_[10], o_[11]);                        \
    op_[3] = make_float4(o_[12], o_[13], o_[14], o_[15]);                      \
} while (0)

    // Prologue: stage chunks 0..6 (28 vmem events in flight)
    STAGE(0); STAGE(1); STAGE(2); STAGE(3); STAGE(4); STAGE(5); STAGE(6);

    // Head: stepped waits while the ring fills
    WAITVM(24); BODY(0, 1);
    WAITVM(28); BODY(1, 1);
    WAITVM(32); BODY(2, 1);
    WAITVM(36); BODY(3, 1);
    WAITVM(40); BODY(4, 1);
    WAITVM(44); BODY(5, 1);
    WAITVM(48); BODY(6, 1);

    // Steady state: counted wait, never drains to 0
#pragma unroll 1
    for (int c = 7; c <= 56; ++c) {
        WAITVM(52);
        BODY(c, 1);
    }

    // Tail: no more staging; waits step down
    WAITVM(52); BODY(57, 0);
    WAITVM(48); BODY(58, 0);
    WAITVM(44); BODY(59, 0);
    WAITVM(40); BODY(60, 0);
    WAITVM(36); BODY(61, 0);
    WAITVM(32); BODY(62, 0);
    WAITVM(28); BODY(63, 0);

#undef BODY
#undef STAGE
}

extern "C" void kernel_launch(void* const* d_in, const int* in_sizes, int n_in,
                              void* d_out, int out_size, void* d_ws, size_t ws_size,
                              hipStream_t stream) {
    const float* in = (const float*)d_in[0];
    const float* alpha = (const float*)d_in[1];
    const float* beta = (const float*)d_in[2];
    float* out = (float*)d_out;

    int total = in_sizes[0];      // 33554432
    int n_rows = total / N_COLS;  // 32768

    dim3 grid((n_rows + 63) / 64);
    dim3 block(64);
    DDK_77644418777662_kernel<<<grid, block, 0, stream>>>(in, out, alpha, beta,
                                                          n_rows);
}

// Round 3
// 283.302 us; speedup vs baseline: 1.0839x; 1.0839x over previous
//
#include <hip/hip_runtime.h>

// l=8, p=1, m=4096, n=1024. One thread-slot per row (nonlinear recurrence,
// bit-exact -> no intra-row parallelism). 32768 rows.
//
// Round-2 lesson: deep in-wave pipelining didn't move the equilibrium
// (118 -> 121 us) because vmcnt retires IN ORDER: a wave that both loads
// and stores couples its load-waits to old-store retirement. Fix: wave
// specialization. Block = 4 waves / 128 rows:
//   wave 0,1: compute (LDS reads, 16-step chain, LDS writes -- ZERO vmem)
//   wave 2:   loader  (pure global_load_lds stream, counted vmcnt)
//   wave 3:   storer  (LDS -> global stores; never waits on retirement,
//                      HW 63-outstanding cap gives ~8 iters of slack)
// Rings: input 6 x 8KB, output 2 x 8KB (64 KB LDS). Raw s_barrier per
// chunk (NOT __syncthreads -- that drains vmcnt and kills the pipeline).
//
// Loader lane mapping (instr q of chunk c): lane L loads 16B of
// row 16q + (L>>2), col-group (L&3)^(((L>>2)>>1)&3), to linear LDS slot
// q*256 + L*4 floats (global_load_lds writes base + lane*16B). 16 rows x
// 64B contiguous per instr. Read-back for row r, group g:
// (r>>4)*256 + ((r&15)*4 + (g ^ ((r>>1)&3)))*4 -- 2-way banks only (free).
//
// Divide: inline-asm correctly-rounded IEEE f32 sequence WITHOUT the
// denorm-mode s_setreg toggles (w in [~0.03,~30], a in (0.001,1] -> all
// Newton intermediates normal -> bit-exact; harness absmax verifies).

#define N_COLS 1024
#define NCHUNK 64
#define KIN 6

#define WAITVM(n) asm volatile("s_waitcnt vmcnt(" #n ")" ::: "memory")
#define WAITLGKM0() asm volatile("s_waitcnt lgkmcnt(0)" ::: "memory")
#define BARRIER() __builtin_amdgcn_s_barrier()

__device__ __forceinline__ float fdiv_rn_exact(float a, float w) {
    float d, n, r0, e, r1, q, e2, q1, e3, f, res;
    unsigned long long sj;
    asm volatile(
        "v_div_scale_f32 %[d], vcc, %[w], %[w], %[a]\n\t"
        "v_div_scale_f32 %[n], %[sj], %[a], %[w], %[a]\n\t"
        "v_rcp_f32 %[r0], %[d]\n\t"
        "s_nop 1\n\t"
        "v_fma_f32 %[e], -%[d], %[r0], 1.0\n\t"
        "v_fma_f32 %[r1], %[e], %[r0], %[r0]\n\t"
        "v_mul_f32 %[q], %[n], %[r1]\n\t"
        "v_fma_f32 %[e2], -%[d], %[q], %[n]\n\t"
        "v_fma_f32 %[q1], %[e2], %[r1], %[q]\n\t"
        "v_fma_f32 %[e3], -%[d], %[q1], %[n]\n\t"
        "v_div_fmas_f32 %[f], %[e3], %[r1], %[q1]\n\t"
        "v_div_fixup_f32 %[res], %[f], %[w], %[a]"
        : [d] "=&v"(d), [n] "=&v"(n), [r0] "=&v"(r0), [e] "=&v"(e),
          [r1] "=&v"(r1), [q] "=&v"(q), [e2] "=&v"(e2), [q1] "=&v"(q1),
          [e3] "=&v"(e3), [f] "=&v"(f), [res] "=v"(res), [sj] "=&s"(sj)
        : [a] "v"(a), [w] "v"(w)
        : "vcc");
    return res;
}

__device__ __forceinline__ float stepf(float w, float x, float a, float b) {
    // (w + a/w) - b*x, all RN, IEEE divide, no fma contraction.
    return __fsub_rn(__fadd_rn(w, fdiv_rn_exact(a, w)), __fmul_rn(b, x));
}

__global__ __launch_bounds__(256) void DDK_77644418777662_kernel(
    const float* __restrict__ in, float* __restrict__ out,
    const float* __restrict__ alpha, const float* __restrict__ beta,
    int n_rows) {
    __shared__ float ibuf[KIN * 2048];  // 6 input chunk slots (128 rows x 16 f)
    __shared__ float obuf[2 * 2048];    // 2 output chunk slots

    const int tid = threadIdx.x;
    const int wid = tid >> 6;
    const int lane = tid & 63;
    const int row_base = blockIdx.x * 128;
    if (row_base >= n_rows) return;  // block-uniform; before any barrier

    // shared lane decomposition for loader/storer
    const int t = lane >> 2;                 // row within 16-row group
    const int u = lane & 3;
    const int cg = u ^ ((t >> 1) & 3);       // swizzled col-group

    if (wid == 2) {
        // ---------------- loader: pure global_load_lds stream ----------------
        const float* src0 = in + (size_t)(row_base + t) * N_COLS + cg * 4;

#define STAGE_AT(S, C) do {                                                    \
    float* dst_ = ibuf + (S) * 2048;                                           \
    const float* s_ = src0 + (size_t)(C) * 16;                                 \
    _Pragma("unroll")                                                          \
    for (int q_ = 0; q_ < 8; ++q_) {                                           \
        __builtin_amdgcn_global_load_lds(                                      \
            (const __attribute__((address_space(1))) void*)(s_ + q_ * 16 * N_COLS), \
            (__attribute__((address_space(3))) void*)(dst_ + q_ * 256), 16, 0, 0);  \
    }                                                                          \
} while (0)

        WAITVM(0);  // clean slate for exact counting
        STAGE_AT(0, 0); STAGE_AT(1, 1); STAGE_AT(2, 2);
        STAGE_AT(3, 3); STAGE_AT(4, 4);
        WAITVM(32);  // chunk 0 complete (40 outstanding -> 32)

        int slot = KIN - 1;
#pragma unroll 1
        for (int c = 0; c < NCHUNK; ++c) {
            BARRIER();
            if (c <= NCHUNK - KIN) {         // c <= 58: stage chunk c+5
                STAGE_AT(slot, c + KIN - 1);
                WAITVM(32);                  // chunk c+1 complete by next barrier
                if (++slot == KIN) slot = 0;
            } else if (c == 59) { WAITVM(24); }
            else if (c == 60) { WAITVM(16); }
            else if (c == 61) { WAITVM(8); }
            else if (c == 62) { WAITVM(0); }
            // c == 63: nothing left to wait for
        }
        BARRIER();  // epilogue
#undef STAGE_AT

    } else if (wid == 3) {
        // ---------------- storer: LDS -> global, pure store stream -----------
        float* dst0 = out + (size_t)(row_base + t) * N_COLS + cg * 4;

#define STORE_CHUNK(C) do {                                                    \
    const float* ob_ = obuf + ((C) & 1) * 2048;                                \
    float4 v_[8];                                                              \
    _Pragma("unroll")                                                          \
    for (int q_ = 0; q_ < 8; ++q_)                                             \
        v_[q_] = *(const float4*)(ob_ + q_ * 256 + lane * 4);                  \
    WAITLGKM0();                                                               \
    _Pragma("unroll")                                                          \
    for (int q_ = 0; q_ < 8; ++q_)                                             \
        *(float4*)(dst0 + (size_t)q_ * 16 * N_COLS + (size_t)(C) * 16) = v_[q_]; \
} while (0)

#pragma unroll 1
        for (int c = 0; c < NCHUNK; ++c) {
            BARRIER();
            if (c >= 1) STORE_CHUNK(c - 1);
        }
        BARRIER();  // epilogue
        STORE_CHUNK(NCHUNK - 1);
#undef STORE_CHUNK

    } else {
        // ---------------- compute waves 0,1: zero vmem in the loop -----------
        const float a = alpha[0];
        const float b = beta[0];

        const int r = (wid << 6) + lane;     // row in block: 0..127
        const int rq = r >> 4, rr = r & 15;
        const int s = (rr >> 1) & 3;
        const int off0 = rq * 256 + (rr * 4 + (0 ^ s)) * 4;
        const int off1 = rq * 256 + (rr * 4 + (1 ^ s)) * 4;
        const int off2 = rq * 256 + (rr * 4 + (2 ^ s)) * 4;
        const int off3 = rq * 256 + (rr * 4 + (3 ^ s)) * 4;

        float w = 1.0f;
        int rslot = 0;
#pragma unroll 1
        for (int c = 0; c < NCHUNK; ++c) {
            BARRIER();
            const float* ib = ibuf + rslot * 2048;
            float4 xa = *(const float4*)(ib + off0);
            float4 xb = *(const float4*)(ib + off1);
            float4 xc = *(const float4*)(ib + off2);
            float4 xd = *(const float4*)(ib + off3);
            float x[16] = {xa.x, xa.y, xa.z, xa.w, xb.x, xb.y, xb.z, xb.w,
                           xc.x, xc.y, xc.z, xc.w, xd.x, xd.y, xd.z, xd.w};
            float o[16];
            o[0] = w;
#pragma unroll
            for (int i = 1; i < 16; ++i) { w = stepf(w, x[i - 1], a, b); o[i] = w; }
            w = stepf(w, x[15], a, b);  // cross-chunk advance (extra on last: harmless)

            float* ob = obuf + (c & 1) * 2048;
            *(float4*)(ob + off0) = make_float4(o[0], o[1], o[2], o[3]);
            *(float4*)(ob + off1) = make_float4(o[4], o[5], o[6], o[7]);
            *(float4*)(ob + off2) = make_float4(o[8], o[9], o[10], o[11]);
            *(float4*)(ob + off3) = make_float4(o[12], o[13], o[14], o[15]);
            WAITLGKM0();  // ds_writes visible before barrier (storer reads next iter)

            if (++rslot == KIN) rslot = 0;
        }
        BARRIER();  // epilogue
    }
}

extern "C" void kernel_launch(void* const* d_in, const int* in_sizes, int n_in,
                              void* d_out, int out_size, void* d_ws, size_t ws_size,
                              hipStream_t stream) {
    const float* in = (const float*)d_in[0];
    const float* alpha = (const float*)d_in[1];
    const float* beta = (const float*)d_in[2];
    float* out = (float*)d_out;

    int total = in_sizes[0];      // 33554432
    int n_rows = total / N_COLS;  // 32768

    dim3 grid(n_rows / 128);      // 256 blocks, 1 per CU
    dim3 block(256);              // 4 waves: 2 compute + loader + storer
    DDK_77644418777662_kernel<<<grid, block, 0, stream>>>(in, out, alpha, beta,
                                                          n_rows);
}

// Round 4
// 271.023 us; speedup vs baseline: 1.1330x; 1.0453x over previous
//
#include <hip/hip_runtime.h>

// l=8, p=1, m=4096, n=1024. One thread-slot per row (nonlinear recurrence,
// bit-exact -> no intra-row parallelism). 32768 rows, row stride 4 KB.
//
// Round 0-3 lesson: three different structures all equilibrate at ~1.8 us
// per 16-float column step => not pipeline depth, not vmcnt coupling.
// Theory: column-synchronized traversal touches only a ~64-384 B window of
// every 4 KB row => HBM-channel / L2-bank aliasing (low address bits fixed
// chip-wide) => ~30% BW cap + huge loaded latency. Also 64 B store granule
// caused 46% write amplification (WRITE_SIZE 187 MB for 128 MB output).
//
// This version: 512 blocks x 64 rows, 3 waves (compute / loader / storer).
//  - chunk = 32 floats = 128 B per row: every load & store instruction
//    moves 8 rows x one FULL aligned 128 B sector (no partial sectors).
//  - ring = 8 slots x 8 KB, 7 chunks in flight with one loader wave
//    (56 gload_lds <= 63 vmcnt cap) => ~1 KB of every 4 KB row in flight,
//    x2 blocks/CU (80 KB LDS each) = 128 KB/CU outstanding.
//  - counted vmcnt (never 0 in steady state), raw s_barrier, obuf dbuf.
//
// Lane mapping (both loader & storer), instr q of chunk c:
//   lane L -> row 8q + (L>>3), col-group cg = (L&7) ^ (L>>3)  [XOR swizzle]
//   LDS float offset (linear, gload_lds-compatible): slot*2048 + q*256 + L*4
// Compute read-back for row r (h=r&7, q=r>>3), group g:
//   slot*2048 + q*256 + h*32 + ((g^h)*4)  -> bank residue (g^h)*4: per
//   16-lane phase all 8 quad-banks x2 = 2-way only (free, m136).
//
// Divide: inline-asm correctly-rounded IEEE f32 (validated absmax 0.0 in
// round 3) without denorm-mode toggles (all intermediates normal here).

#define N_COLS 1024
#define DC 32      // floats per chunk per row (128 B)
#define NDC 32     // chunks per row
#define RING 8
#define ROWS 64
#define SLOTF 2048 // floats per slot (64 rows x 32)

#define WAITVM(n) asm volatile("s_waitcnt vmcnt(" #n ")" ::: "memory")
#define WAITLGKM0() asm volatile("s_waitcnt lgkmcnt(0)" ::: "memory")
#define BARRIER() __builtin_amdgcn_s_barrier()

__device__ __forceinline__ float fdiv_rn_exact(float a, float w) {
    float d, n, r0, e, r1, q, e2, q1, e3, f, res;
    unsigned long long sj;
    asm volatile(
        "v_div_scale_f32 %[d], vcc, %[w], %[w], %[a]\n\t"
        "v_div_scale_f32 %[n], %[sj], %[a], %[w], %[a]\n\t"
        "v_rcp_f32 %[r0], %[d]\n\t"
        "s_nop 1\n\t"
        "v_fma_f32 %[e], -%[d], %[r0], 1.0\n\t"
        "v_fma_f32 %[r1], %[e], %[r0], %[r0]\n\t"
        "v_mul_f32 %[q], %[n], %[r1]\n\t"
        "v_fma_f32 %[e2], -%[d], %[q], %[n]\n\t"
        "v_fma_f32 %[q1], %[e2], %[r1], %[q]\n\t"
        "v_fma_f32 %[e3], -%[d], %[q1], %[n]\n\t"
        "v_div_fmas_f32 %[f], %[e3], %[r1], %[q1]\n\t"
        "v_div_fixup_f32 %[res], %[f], %[w], %[a]"
        : [d] "=&v"(d), [n] "=&v"(n), [r0] "=&v"(r0), [e] "=&v"(e),
          [r1] "=&v"(r1), [q] "=&v"(q), [e2] "=&v"(e2), [q1] "=&v"(q1),
          [e3] "=&v"(e3), [f] "=&v"(f), [res] "=v"(res), [sj] "=&s"(sj)
        : [a] "v"(a), [w] "v"(w)
        : "vcc");
    return res;
}

__device__ __forceinline__ float stepf(float w, float x, float a, float b) {
    // (w + a/w) - b*x, all RN, IEEE divide, no fma contraction.
    return __fsub_rn(__fadd_rn(w, fdiv_rn_exact(a, w)), __fmul_rn(b, x));
}

__global__ __launch_bounds__(192) void DDK_77644418777662_kernel(
    const float* __restrict__ in, float* __restrict__ out,
    const float* __restrict__ alpha, const float* __restrict__ beta,
    int n_rows) {
    __shared__ float ibuf[RING * SLOTF];  // 64 KB: 8 input chunk slots
    __shared__ float obuf[2 * SLOTF];     // 16 KB: 2 output chunk slots

    const int tid = threadIdx.x;
    const int wid = tid >> 6;
    const int lane = tid & 63;
    const int row_base = blockIdx.x * ROWS;
    if (row_base >= n_rows) return;  // block-uniform; before any barrier

    const int lr = lane >> 3;      // row within 8-row group
    const int cg = (lane & 7) ^ lr;  // swizzled 16B col-group

    if (wid == 1) {
        // ---------------- loader: pure global_load_lds stream ----------------
        const float* src0 = in + (size_t)(row_base + lr) * N_COLS + cg * 4;

#define STAGE_AT(S, C) do {                                                    \
    float* dst_ = ibuf + (S) * SLOTF;                                          \
    const float* s_ = src0 + (C) * DC;                                         \
    _Pragma("unroll")                                                          \
    for (int q_ = 0; q_ < 8; ++q_) {                                           \
        __builtin_amdgcn_global_load_lds(                                      \
            (const __attribute__((address_space(1))) void*)(s_ + (size_t)q_ * 8 * N_COLS), \
            (__attribute__((address_space(3))) void*)(dst_ + q_ * 256), 16, 0, 0);         \
    }                                                                          \
} while (0)

        WAITVM(0);  // clean slate for exact counting
        STAGE_AT(0, 0); STAGE_AT(1, 1); STAGE_AT(2, 2); STAGE_AT(3, 3);
        STAGE_AT(4, 4); STAGE_AT(5, 5); STAGE_AT(6, 6);   // 56 outstanding
        WAITVM(48);  // chunk 0 complete

#pragma unroll 1
        for (int c = 0; c < NDC; ++c) {
            BARRIER();
            if (c <= NDC - RING) {            // c <= 24: stage chunk c+7
                STAGE_AT((c + 7) & 7, c + 7); // -> 56 outstanding
                WAITVM(48);                   // chunk c+1 complete
            } else if (c == 25) { WAITVM(40); }
            else if (c == 26) { WAITVM(32); }
            else if (c == 27) { WAITVM(24); }
            else if (c == 28) { WAITVM(16); }
            else if (c == 29) { WAITVM(8); }
            else if (c == 30) { WAITVM(0); }
            // c == 31: nothing left to wait for
        }
        BARRIER();  // epilogue
#undef STAGE_AT

    } else if (wid == 2) {
        // ---------------- storer: LDS -> global, full 128B sectors -----------
        float* dst0 = out + (size_t)(row_base + lr) * N_COLS + cg * 4;

#define STORE_CHUNK(C) do {                                                    \
    const float* ob_ = obuf + ((C) & 1) * SLOTF;                               \
    float4 v_[8];                                                              \
    _Pragma("unroll")                                                          \
    for (int q_ = 0; q_ < 8; ++q_)                                             \
        v_[q_] = *(const float4*)(ob_ + q_ * 256 + lane * 4);                  \
    WAITLGKM0();                                                               \
    _Pragma("unroll")                                                          \
    for (int q_ = 0; q_ < 8; ++q_)                                             \
        *(float4*)(dst0 + (size_t)q_ * 8 * N_COLS + (C) * DC) = v_[q_];        \
} while (0)

#pragma unroll 1
        for (int c = 0; c < NDC; ++c) {
            BARRIER();
            if (c >= 1) STORE_CHUNK(c - 1);
        }
        BARRIER();  // epilogue
        STORE_CHUNK(NDC - 1);
#undef STORE_CHUNK

    } else {
        // ---------------- compute wave 0: zero vmem in the loop --------------
        const float a = alpha[0];
        const float b = beta[0];

        const int q = lane >> 3, h = lane & 7;
        const int base_f = q * 256 + h * 32;
        int off[8];
#pragma unroll
        for (int g = 0; g < 8; ++g) off[g] = base_f + ((g ^ h) * 4);

        float w = 1.0f;
#pragma unroll 1
        for (int c = 0; c < NDC; ++c) {
            BARRIER();
            const float* ib = ibuf + (c & 7) * SLOTF;
            float4 v[8];
#pragma unroll
            for (int g = 0; g < 8; ++g) v[g] = *(const float4*)(ib + off[g]);
            float x[32];
#pragma unroll
            for (int g = 0; g < 8; ++g) {
                x[g * 4 + 0] = v[g].x; x[g * 4 + 1] = v[g].y;
                x[g * 4 + 2] = v[g].z; x[g * 4 + 3] = v[g].w;
            }
            float o[32];
            o[0] = w;
#pragma unroll
            for (int i = 1; i < 32; ++i) { w = stepf(w, x[i - 1], a, b); o[i] = w; }
            w = stepf(w, x[31], a, b);  // cross-chunk advance (extra on last: harmless)

            float* ob = obuf + (c & 1) * SLOTF;
#pragma unroll
            for (int g = 0; g < 8; ++g)
                *(float4*)(ob + off[g]) = make_float4(o[g * 4 + 0], o[g * 4 + 1],
                                                      o[g * 4 + 2], o[g * 4 + 3]);
            WAITLGKM0();  // ds_writes visible before next barrier
        }
        BARRIER();  // epilogue
    }
}

extern "C" void kernel_launch(void* const* d_in, const int* in_sizes, int n_in,
                              void* d_out, int out_size, void* d_ws, size_t ws_size,
                              hipStream_t stream) {
    const float* in = (const float*)d_in[0];
    const float* alpha = (const float*)d_in[1];
    const float* beta = (const float*)d_in[2];
    float* out = (float*)d_out;

    int total = in_sizes[0];      // 33554432
    int n_rows = total / N_COLS;  // 32768

    dim3 grid(n_rows / ROWS);     // 512 blocks, 2 per CU (80 KB LDS each)
    dim3 block(192);              // 3 waves: compute + loader + storer
    DDK_77644418777662_kernel<<<grid, block, 0, stream>>>(in, out, alpha, beta,
                                                          n_rows);
}

// Round 6
// 256.248 us; speedup vs baseline: 1.1983x; 1.0577x over previous
//
#include <hip/hip_runtime.h>

// l=8, p=1, m=4096, n=1024. One thread-slot per row (nonlinear recurrence,
// bit-exact -> no intra-row parallelism). 32768 rows, row stride 4 KB.
//
// RESUBMISSION of round 5: the bench infra failed twice before launch
// (no compile/test error). Deadlock audit found barrier counts equal (35)
// across all 7 waves, no ibuf/obuf race, no OOB -- resubmitting unchanged
// to run the discriminating experiment.
//
// Rounds 0-4: per-column-step time invariant ~1.75 us/16f across five
// structures (depth, specialization, sector granularity all ruled out).
// Theory: chip-wide column-synchronized march touches only ~64-384 B of
// every 4 KB row at any instant -> address-bit aliasing caps the pattern
// at ~2.3 TB/s. This version restructures to 512 B-per-row read bursts
// and 256 B-per-row write bursts with many concurrent vmem waves.
//
// Block = 7 waves (448 thr), 64 rows (256 KB slab). 2 blocks/CU (80 KB LDS).
//   wave 0   : compute (64 rows, zero vmem in loop)
//   waves 1-4: loaders -- pair-staged global_load_lds, 512 B/row bursts
//   waves 5-6: storers -- obuf->regs->global, 256 B/row bursts
// Groups of G=64 cols; NG=16 periods; pairs e = groups {2e,2e+1} staged
// as one 512 B/row event into a 2-slot pair ring (2 x 32 KB). obuf = one
// 16 KB group slot; race-freedom via 2 barriers/period (storers read obuf
// to regs before B2; compute overwrites after B2).
//
// LDS swizzle (both-sides-or-neither, rule #21): loader pre-swizzles the
// GLOBAL source (perm(u) = (u&16)|((u&15)^(r&7)), an involution within the
// 512 B span -> same sectors, same coalescing), LDS dest stays linear
// (base + lane*16 as gload_lds requires). Compute/storers apply the same
// XOR on read -> all LDS access 2-way bank aliasing only (free, m136).
//
// Divide: inline-asm correctly-rounded IEEE f32 (validated absmax 0.0 in
// rounds 3-4), no denorm-mode toggles needed for this value range.

#define N_COLS 1024
#define NG 16  // 16 groups x 64 cols

#define WAITVM0() asm volatile("s_waitcnt vmcnt(0)" ::: "memory")
#define WAITLGKM0() asm volatile("s_waitcnt lgkmcnt(0)" ::: "memory")
#define BARRIER() __builtin_amdgcn_s_barrier()

__device__ __forceinline__ float fdiv_rn_exact(float a, float w) {
    float d, n, r0, e, r1, q, e2, q1, e3, f, res;
    unsigned long long sj;
    asm volatile(
        "v_div_scale_f32 %[d], vcc, %[w], %[w], %[a]\n\t"
        "v_div_scale_f32 %[n], %[sj], %[a], %[w], %[a]\n\t"
        "v_rcp_f32 %[r0], %[d]\n\t"
        "s_nop 1\n\t"
        "v_fma_f32 %[e], -%[d], %[r0], 1.0\n\t"
        "v_fma_f32 %[r1], %[e], %[r0], %[r0]\n\t"
        "v_mul_f32 %[q], %[n], %[r1]\n\t"
        "v_fma_f32 %[e2], -%[d], %[q], %[n]\n\t"
        "v_fma_f32 %[q1], %[e2], %[r1], %[q]\n\t"
        "v_fma_f32 %[e3], -%[d], %[q1], %[n]\n\t"
        "v_div_fmas_f32 %[f], %[e3], %[r1], %[q1]\n\t"
        "v_div_fixup_f32 %[res], %[f], %[w], %[a]"
        : [d] "=&v"(d), [n] "=&v"(n), [r0] "=&v"(r0), [e] "=&v"(e),
          [r1] "=&v"(r1), [q] "=&v"(q), [e2] "=&v"(e2), [q1] "=&v"(q1),
          [e3] "=&v"(e3), [f] "=&v"(f), [res] "=v"(res), [sj] "=&s"(sj)
        : [a] "v"(a), [w] "v"(w)
        : "vcc");
    return res;
}

__device__ __forceinline__ float stepf(float w, float x, float a, float b) {
    // (w + a/w) - b*x, all RN, IEEE divide, no fma contraction.
    return __fsub_rn(__fadd_rn(w, fdiv_rn_exact(a, w)), __fmul_rn(b, x));
}

__global__ __launch_bounds__(448) void DDK_77644418777662_kernel(
    const float* __restrict__ in, float* __restrict__ out,
    const float* __restrict__ alpha, const float* __restrict__ beta,
    int n_rows) {
    __shared__ float ibuf[2 * 8192];  // 64 KB: 2 pair-slots (64 rows x 128 f)
    __shared__ float obuf[4096];      // 16 KB: 1 group slot (64 rows x 64 f)

    const int tid = threadIdx.x;
    const int wid = tid >> 6;
    const int lane = tid & 63;
    const int row_base = blockIdx.x * 64;
    if (row_base >= n_rows) return;  // block-uniform, before any barrier

    if (wid >= 1 && wid <= 4) {
        // ---------------- loaders: 512 B/row burst events ----------------
        const int lw = wid - 1;                  // 0..3
        const int rsub = lw * 2 + (lane >> 5);   // 0..7 (row mod 8 per instr)
        const int u = lane & 31;                 // 16B-unit within 512 B span
        const int pu = (u & 16) | ((u & 15) ^ rsub);  // pre-swizzled source unit
        const float* srcb = in + (size_t)(row_base + rsub) * N_COLS + pu * 4;

#define ISSUE_EVENT(E) do {                                                    \
    const int q_ = (E) & 1;                                                    \
    _Pragma("unroll")                                                          \
    for (int k_ = 0; k_ < 8; ++k_) {                                           \
        __builtin_amdgcn_global_load_lds(                                      \
            (const __attribute__((address_space(1))) void*)                    \
                (srcb + (E) * 128 + k_ * 8192),                                \
            (__attribute__((address_space(3))) void*)                          \
                (ibuf + q_ * 8192 + k_ * 1024 + lw * 256),                     \
            16, 0, 0);                                                         \
    }                                                                          \
} while (0)

        WAITVM0();          // clean slate
        ISSUE_EVENT(0);     // pair 0 -> slot 0
        WAITVM0();          // pair 0 landed before anyone computes
        BARRIER();          // prologue barrier
#pragma unroll 1
        for (int g = 0; g <= NG; ++g) {
            BARRIER();      // B1
            BARRIER();      // B2
            if ((g & 1) == 0) {
                int p = (g >> 1) + 1;            // issue pair p at period 2p-2
                if (p <= 7) ISSUE_EVENT(p);      // slot p&1 free since 2p-3
            } else if (g <= 13) {
                WAITVM0();  // pair (g+1)/2 landed; needed at period g+1
            }
        }
#undef ISSUE_EVENT

    } else if (wid == 0) {
        // ---------------- compute: zero vmem in the loop ------------------
        const float a = alpha[0];
        const float b = beta[0];
        const int c = lane & 7;
        float* ob = obuf + lane * 64;

        float w = 1.0f;
        BARRIER();          // prologue barrier
#pragma unroll 1
        for (int g = 0; g <= NG; ++g) {
            BARRIER();      // B1
            BARRIER();      // B2  (storers have drained obuf[g-1] to regs)
            if (g < NG) {
                const float* ib = ibuf + ((g >> 1) & 1) * 8192 + lane * 128 +
                                  (g & 1) * 64;
                // unit W lives at ib + ((W^c)<<2); data is 4 consecutive cols
                float4 x0 = *(const float4*)(ib + ((0 ^ c) << 2));
                float4 x1 = *(const float4*)(ib + ((1 ^ c) << 2));
                float4 x2 = *(const float4*)(ib + ((2 ^ c) << 2));
                float4 x3 = *(const float4*)(ib + ((3 ^ c) << 2));
                float4 x4 = *(const float4*)(ib + ((4 ^ c) << 2));
                float4 x5 = *(const float4*)(ib + ((5 ^ c) << 2));
                float4 x6 = *(const float4*)(ib + ((6 ^ c) << 2));
                float4 x7 = *(const float4*)(ib + ((7 ^ c) << 2));
                float4 x8 = *(const float4*)(ib + ((8 ^ c) << 2));
                float4 x9 = *(const float4*)(ib + ((9 ^ c) << 2));
                float4 xa = *(const float4*)(ib + ((10 ^ c) << 2));
                float4 xb_ = *(const float4*)(ib + ((11 ^ c) << 2));
                float4 xc_ = *(const float4*)(ib + ((12 ^ c) << 2));
                float4 xd = *(const float4*)(ib + ((13 ^ c) << 2));
                float4 xe = *(const float4*)(ib + ((14 ^ c) << 2));
                float4 xf = *(const float4*)(ib + ((15 ^ c) << 2));

#define UNITSTEP(W_, XU) do {                                                  \
    float4 o_;                                                                 \
    o_.x = w; w = stepf(w, XU.x, a, b);                                        \
    o_.y = w; w = stepf(w, XU.y, a, b);                                        \
    o_.z = w; w = stepf(w, XU.z, a, b);                                        \
    o_.w = w; w = stepf(w, XU.w, a, b);                                        \
    *(float4*)(ob + (((W_) ^ c) << 2)) = o_;                                   \
} while (0)
                UNITSTEP(0, x0);  UNITSTEP(1, x1);  UNITSTEP(2, x2);
                UNITSTEP(3, x3);  UNITSTEP(4, x4);  UNITSTEP(5, x5);
                UNITSTEP(6, x6);  UNITSTEP(7, x7);  UNITSTEP(8, x8);
                UNITSTEP(9, x9);  UNITSTEP(10, xa); UNITSTEP(11, xb_);
                UNITSTEP(12, xc_); UNITSTEP(13, xd); UNITSTEP(14, xe);
                UNITSTEP(15, xf);
#undef UNITSTEP
                // trailing step above already advanced w across the group
                // boundary (last group's extra step is dead -- never stored).
                WAITLGKM0();  // obuf writes visible before next B1
            }
        }

    } else {
        // ---------------- storers: 256 B/row burst stores -----------------
        const int sw = wid - 5;                  // 0..1
        const int rsub = sw * 4 + (lane >> 4);   // 0..7
        const int j = lane & 15;
        const int m = j ^ rsub;                  // XOR un-swizzle
        const float* obb = obuf + rsub * 64 + m * 4;  // + k*512
        float* dstb = out + (size_t)(row_base + rsub) * N_COLS + j * 4;

        BARRIER();          // prologue barrier
#pragma unroll 1
        for (int g = 0; g <= NG; ++g) {
            BARRIER();      // B1
            float4 v0, v1, v2, v3, v4, v5, v6, v7;
            if (g >= 1) {   // drain obuf (group g-1) to regs before B2
                v0 = *(const float4*)(obb + 0 * 512);
                v1 = *(const float4*)(obb + 1 * 512);
                v2 = *(const float4*)(obb + 2 * 512);
                v3 = *(const float4*)(obb + 3 * 512);
                v4 = *(const float4*)(obb + 4 * 512);
                v5 = *(const float4*)(obb + 5 * 512);
                v6 = *(const float4*)(obb + 6 * 512);
                v7 = *(const float4*)(obb + 7 * 512);
                WAITLGKM0();
            }
            BARRIER();      // B2 (compute may now overwrite obuf)
            if (g >= 1) {
                float* d = dstb + (size_t)(g - 1) * 64;
                *(float4*)(d + 0 * 8192) = v0;
                *(float4*)(d + 1 * 8192) = v1;
                *(float4*)(d + 2 * 8192) = v2;
                *(float4*)(d + 3 * 8192) = v3;
                *(float4*)(d + 4 * 8192) = v4;
                *(float4*)(d + 5 * 8192) = v5;
                *(float4*)(d + 6 * 8192) = v6;
                *(float4*)(d + 7 * 8192) = v7;
            }
        }
    }
}

extern "C" void kernel_launch(void* const* d_in, const int* in_sizes, int n_in,
                              void* d_out, int out_size, void* d_ws, size_t ws_size,
                              hipStream_t stream) {
    const float* in = (const float*)d_in[0];
    const float* alpha = (const float*)d_in[1];
    const float* beta = (const float*)d_in[2];
    float* out = (float*)d_out;

    int total = in_sizes[0];      // 33554432
    int n_rows = total / N_COLS;  // 32768

    dim3 grid(n_rows / 64);       // 512 blocks, 64 rows each; 2 blocks/CU
    dim3 block(448);              // 7 waves: 1 compute + 4 loaders + 2 storers
    DDK_77644418777662_kernel<<<grid, block, 0, stream>>>(in, out, alpha, beta,
                                                          n_rows);
}